// Round 3
// baseline (773.366 us; speedup 1.0000x reference)
//
#include <hip/hip_runtime.h>
#include <hip/hip_bf16.h>
#include <hip/hip_fp16.h>

// tanh-RNN + FC on MI355X.
// conv_w -> gemm_xproj (f16 MFMA, swizzled xp output) -> rnn_scan3 (32 blocks,
// batch-split, NO inter-block sync; W 3/4 in pinned VGPRs + 1/4 L2-streamed)
// -> gemm_logits (in-place over d_out).

typedef _Float16 half8 __attribute__((ext_vector_type(8)));
typedef float f32x4 __attribute__((ext_vector_type(4)));

// ws layout (bytes)
#define XPW_OFF   0UL            // 64MB x_proj f16 (swizzled)
#define WIH_OFF   67108864UL     // 512KB
#define WHH_OFF   67633152UL     // 512KB row-major f16
#define FCW_OFF   68157440UL     // 256KB
#define BIAS_OFF  68419584UL     // 2KB
#define WSTR_OFF  68421632UL     // 128KB streamed W tiles (n=3), pre-swizzled

// ---------------------------------------------------------------------------
// Weight conversion + pre-swizzled stream tiles.
// wstr layout: [w(8)][s(16)][lane(64)][8] f16; value = Whh[w*64+48+(l&15)][s*32+(l>>4)*8+i]
// ---------------------------------------------------------------------------
__global__ void conv_w(const float* __restrict__ Wih, const float* __restrict__ Whh,
                       const float* __restrict__ fcw, const float* __restrict__ bih,
                       const float* __restrict__ bhh,
                       _Float16* __restrict__ wih_h, _Float16* __restrict__ whh_h,
                       _Float16* __restrict__ fcw_h, float* __restrict__ bias2,
                       _Float16* __restrict__ wstr) {
    int idx = blockIdx.x * 256 + threadIdx.x;
    if (idx < 262144) {
        wih_h[idx] = (_Float16)Wih[idx];
        whh_h[idx] = (_Float16)Whh[idx];
    }
    if (idx < 131072) fcw_h[idx] = (_Float16)fcw[idx];
    if (idx < 512) bias2[idx] = bih[idx] + bhh[idx];
    if (idx < 65536) {
        const int w = idx >> 13, s = (idx >> 9) & 15, l = (idx >> 3) & 63, i = idx & 7;
        wstr[idx] = (_Float16)Whh[(size_t)(w * 64 + 48 + (l & 15)) * 512 + s * 32 + (l >> 4) * 8 + i];
    }
}

// ---------------------------------------------------------------------------
// K1: x_proj = states @ W_ih^T + bias2, written in scan-consumption swizzle:
// addr = ((b>>4)*128 + t)*8192 + (col>>6)*1024 + ((b>>2)&3)*256 + (col&15)*16
//        + ((col>>4)&3)*4 + (b&3),  where flat row = b*128+t.
// ---------------------------------------------------------------------------
__global__ __launch_bounds__(256) void gemm_xproj(const float* __restrict__ A,
                                                  const _Float16* __restrict__ Bw,
                                                  const float* __restrict__ bias2,
                                                  _Float16* __restrict__ out) {
    __shared__ _Float16 As[128 * 32];
    __shared__ _Float16 Bs[128 * 32];
    const int tid = threadIdx.x;
    const int m0 = (blockIdx.x >> 2) * 128;
    const int n0 = (blockIdx.x & 3) * 128;
    const int lane = tid & 63, w = tid >> 6;
    const int wr = (w >> 1) * 64, wc = (w & 1) * 64;
    const int ln = lane & 15, kg = lane >> 4;

    f32x4 acc[4][4];
#pragma unroll
    for (int m = 0; m < 4; m++)
#pragma unroll
        for (int n = 0; n < 4; n++) acc[m][n] = (f32x4)0.0f;

    const int sr = tid >> 1;
    const int sc = (tid & 1) * 16;

    for (int k0 = 0; k0 < 512; k0 += 32) {
        {
            const float* ga = A + (size_t)(m0 + sr) * 512 + k0 + sc;
            float4 f0 = *(const float4*)(ga + 0);
            float4 f1 = *(const float4*)(ga + 4);
            float4 f2 = *(const float4*)(ga + 8);
            float4 f3 = *(const float4*)(ga + 12);
            half8 h0, h1;
            h0[0] = (_Float16)f0.x; h0[1] = (_Float16)f0.y; h0[2] = (_Float16)f0.z; h0[3] = (_Float16)f0.w;
            h0[4] = (_Float16)f1.x; h0[5] = (_Float16)f1.y; h0[6] = (_Float16)f1.z; h0[7] = (_Float16)f1.w;
            h1[0] = (_Float16)f2.x; h1[1] = (_Float16)f2.y; h1[2] = (_Float16)f2.z; h1[3] = (_Float16)f2.w;
            h1[4] = (_Float16)f3.x; h1[5] = (_Float16)f3.y; h1[6] = (_Float16)f3.z; h1[7] = (_Float16)f3.w;
            *(half8*)&As[sr * 32 + sc] = h0;
            *(half8*)&As[sr * 32 + sc + 8] = h1;
        }
        {
            const _Float16* gb = Bw + (size_t)(n0 + sr) * 512 + k0 + sc;
            *(half8*)&Bs[sr * 32 + sc] = *(const half8*)(gb);
            *(half8*)&Bs[sr * 32 + sc + 8] = *(const half8*)(gb + 8);
        }
        __syncthreads();
        half8 af[4], bf[4];
#pragma unroll
        for (int m = 0; m < 4; m++) af[m] = *(const half8*)&As[(wr + m * 16 + ln) * 32 + kg * 8];
#pragma unroll
        for (int n = 0; n < 4; n++) bf[n] = *(const half8*)&Bs[(wc + n * 16 + ln) * 32 + kg * 8];
#pragma unroll
        for (int m = 0; m < 4; m++)
#pragma unroll
            for (int n = 0; n < 4; n++)
                acc[m][n] = __builtin_amdgcn_mfma_f32_16x16x32_f16(af[m], bf[n], acc[m][n], 0, 0, 0);
        __syncthreads();
    }
#pragma unroll
    for (int m = 0; m < 4; m++)
#pragma unroll
        for (int q = 0; q < 4; q++) {
            const int row = m0 + wr + m * 16 + kg * 4 + q;
            const int b = row >> 7, t = row & 127;
            const size_t rowbase = ((size_t)((b >> 4) * 128 + t)) * 8192
                                 + (size_t)((b >> 2) & 3) * 256 + (b & 3);
#pragma unroll
            for (int n = 0; n < 4; n++) {
                const int col = n0 + wc + n * 16 + ln;
                const float bv = bias2[col];
                const size_t dst = rowbase + (size_t)(col >> 6) * 1024
                                 + (col & 15) * 16 + ((col >> 4) & 3) * 4;
                out[dst] = (_Float16)(acc[m][n][q] + bv);
            }
        }
}

// ---------------------------------------------------------------------------
// Scan v3: 32 blocks x 512 thr (8 waves, 2/SIMD). Wave w owns j-cols
// [w*64, w*64+64): n-tiles 0..2 weights VGPR-resident (192 regs, asm-pinned),
// n-tile 3 streamed from L2 (pre-swizzled wstr). h in k8-major LDS (16KB,
// single buffer, 2 barriers/step). xp loaded as 2xb128 from swizzled layout.
// ---------------------------------------------------------------------------
__global__ __launch_bounds__(512, 2) void rnn_scan3(
    const _Float16* __restrict__ xps,    // swizzled x_proj
    const _Float16* __restrict__ Whh,    // row-major f16
    const _Float16* __restrict__ wstr,   // streamed n=3 tiles
    const int* __restrict__ term,        // [512][128] int32
    const float* __restrict__ h0,        // [512][512] f32
    float* dout) {
    // h LDS, k8-major: f16 addr = (k>>3)*128 + row*8 + (k&7)  (k = 0..511, row = 0..15)
    __shared__ __align__(16) _Float16 hb[8192];
    __shared__ unsigned int term_lds[16][4];
    const int tid = threadIdx.x;
    const int R0 = blockIdx.x * 16;
    const int lane = tid & 63, w = tid >> 6;
    const int ln = lane & 15, kg = lane >> 4;
    _Float16* rnn = (_Float16*)dout;

    // ---- resident weights: n=0..2, full K ----
    half8 wf[48];   // wf[n*16+s]
#pragma unroll
    for (int n = 0; n < 3; n++)
#pragma unroll
        for (int s = 0; s < 16; s++)
            wf[n * 16 + s] = *(const half8*)(Whh + (size_t)(w * 64 + n * 16 + ln) * 512 + s * 32 + kg * 8);
#pragma unroll
    for (int i = 0; i < 48; i++) asm volatile("" : "+v"(wf[i]));

    // ---- h0 -> LDS (f32 -> f16, k8-major) ----
    {
        const int r = tid >> 5, c0 = (tid & 31) * 16;
        const float* gh = h0 + (size_t)(R0 + r) * 512 + c0;
        half8 v0, v1;
#pragma unroll
        for (int i = 0; i < 8; i++) { v0[i] = (_Float16)gh[i]; v1[i] = (_Float16)gh[8 + i]; }
        *(half8*)&hb[(c0 >> 3) * 128 + r * 8] = v0;
        *(half8*)&hb[((c0 >> 3) + 1) * 128 + r * 8] = v1;
    }
    // ---- termination bitmasks ----
    if (tid < 64) {
        const int r = tid >> 2, word = tid & 3;
        unsigned int m = 0;
        for (int b = 0; b < 32; b++)
            m |= (term[(R0 + r) * 128 + word * 32 + b] ? 1u : 0u) << b;
        term_lds[r][word] = m;
    }
    __syncthreads();

    const _Float16* wsb = wstr + (size_t)w * 8192;     // wave's 16 stream frags
    const size_t xbase0 = ((size_t)(R0 >> 4) * 128) * 8192 + w * 1024 + kg * 256 + ln * 16;
    unsigned int tmask[4];

    for (int t = 0; t < 128; ++t) {
        if ((t & 31) == 0) {
#pragma unroll
            for (int q = 0; q < 4; q++) tmask[q] = term_lds[kg * 4 + q][t >> 5];
        }
        // xp for this step (consumed after barrier — full K-loop to land)
        const half8 xv0 = *(const half8*)(xps + xbase0 + (size_t)t * 8192);
        const half8 xv1 = *(const half8*)(xps + xbase0 + (size_t)t * 8192 + 8);

        f32x4 acc[4];
#pragma unroll
        for (int n = 0; n < 4; n++) acc[n] = (f32x4)0.0f;

        // streamed W: rolling 4-deep prefetch (L2-resident)
        half8 wst[4];
#pragma unroll
        for (int p = 0; p < 4; p++) wst[p] = *(const half8*)(wsb + p * 512 + lane * 8);

#pragma unroll
        for (int s = 0; s < 16; s++) {
            const half8 a = *(const half8*)&hb[s * 512 + kg * 128 + ln * 8];
            acc[0] = __builtin_amdgcn_mfma_f32_16x16x32_f16(a, wf[s],      acc[0], 0, 0, 0);
            acc[1] = __builtin_amdgcn_mfma_f32_16x16x32_f16(a, wf[16 + s], acc[1], 0, 0, 0);
            acc[2] = __builtin_amdgcn_mfma_f32_16x16x32_f16(a, wf[32 + s], acc[2], 0, 0, 0);
            acc[3] = __builtin_amdgcn_mfma_f32_16x16x32_f16(a, wst[s & 3], acc[3], 0, 0, 0);
            if (s < 12) wst[s & 3] = *(const half8*)(wsb + (s + 4) * 512 + lane * 8);
        }
        __syncthreads();    // all reads of h(t) complete

        // tanh + rnn_out (unmasked) + h(t+1) to LDS (masked)
#pragma unroll
        for (int n = 0; n < 4; n++)
#pragma unroll
            for (int q = 0; q < 4; q++) {
                const float xvv = (float)((n < 2) ? xv0[n * 4 + q] : xv1[(n - 2) * 4 + q]);
                const float pre = acc[n][q] + xvv;
                const float e = __expf(2.0f * pre);
                const float hn = 1.0f - 2.0f / (e + 1.0f);
                const int col = w * 64 + n * 16 + ln;
                rnn[(size_t)((R0 + kg * 4 + q) * 128 + t) * 512 + col] = (_Float16)hn;
                const _Float16 hv = ((tmask[q] >> (t & 31)) & 1) ? (_Float16)0.0f : (_Float16)hn;
                hb[(col >> 3) * 128 + (kg * 4 + q) * 8 + (col & 7)] = hv;
            }
        __syncthreads();    // h(t+1) visible
    }

    // ---- h_final (masked) -> f32 at d_out + 65536*256 ----
    {
        const int r = tid >> 5, c0 = (tid & 31) * 16;
        half8 v0 = *(const half8*)&hb[(c0 >> 3) * 128 + r * 8];
        half8 v1 = *(const half8*)&hb[((c0 >> 3) + 1) * 128 + r * 8];
        float* gf = dout + (size_t)65536 * 256 + (size_t)(R0 + r) * 512 + c0;
#pragma unroll
        for (int i = 0; i < 8; i++) { gf[i] = (float)v0[i]; gf[8 + i] = (float)v1[i]; }
    }
}

// ---------------------------------------------------------------------------
// K3: logits[65536,256] (f32) = rnn_out(f16, in d_out) @ fc_w^T + fc_b
// ---------------------------------------------------------------------------
__global__ __launch_bounds__(512) void gemm_logits(const _Float16* Arnn,
                                                   const _Float16* __restrict__ Bw,
                                                   const float* __restrict__ biasv,
                                                   float* out) {
    __shared__ _Float16 As[128 * 32];
    __shared__ _Float16 Bs[256 * 32];
    const int tid = threadIdx.x;
    const int m0 = blockIdx.x * 128;
    const int lane = tid & 63, w = tid >> 6;
    const int wr = (w >> 2) * 64, wc = (w & 3) * 64;
    const int ln = lane & 15, kg = lane >> 4;

    f32x4 acc[4][4];
#pragma unroll
    for (int m = 0; m < 4; m++)
#pragma unroll
        for (int n = 0; n < 4; n++) acc[m][n] = (f32x4)0.0f;

    const int ar = tid >> 2, ac = (tid & 3) * 8;
    const int br = tid >> 1, bc = (tid & 1) * 16;

    for (int k0 = 0; k0 < 512; k0 += 32) {
        *(half8*)&As[ar * 32 + ac] = *(const half8*)(Arnn + (size_t)(m0 + ar) * 512 + k0 + ac);
        {
            const _Float16* gb = Bw + (size_t)br * 512 + k0 + bc;
            *(half8*)&Bs[br * 32 + bc] = *(const half8*)(gb);
            *(half8*)&Bs[br * 32 + bc + 8] = *(const half8*)(gb + 8);
        }
        __syncthreads();
        half8 af[4], bf[4];
#pragma unroll
        for (int m = 0; m < 4; m++) af[m] = *(const half8*)&As[(wr + m * 16 + ln) * 32 + kg * 8];
#pragma unroll
        for (int n = 0; n < 4; n++) bf[n] = *(const half8*)&Bs[(wc + n * 16 + ln) * 32 + kg * 8];
#pragma unroll
        for (int m = 0; m < 4; m++)
#pragma unroll
            for (int n = 0; n < 4; n++)
                acc[m][n] = __builtin_amdgcn_mfma_f32_16x16x32_f16(af[m], bf[n], acc[m][n], 0, 0, 0);
        __syncthreads();
    }
#pragma unroll
    for (int m = 0; m < 4; m++)
#pragma unroll
        for (int n = 0; n < 4; n++) {
            const int col = wc + n * 16 + ln;
            const float bv = biasv[col];
#pragma unroll
            for (int q = 0; q < 4; q++) {
                const int row = m0 + wr + m * 16 + kg * 4 + q;
                out[(size_t)row * 256 + col] = acc[m][n][q] + bv;
            }
        }
}

// ---------------------------------------------------------------------------
extern "C" void kernel_launch(void* const* d_in, const int* in_sizes, int n_in,
                              void* d_out, int out_size, void* d_ws, size_t ws_size,
                              hipStream_t stream) {
    const float* states = (const float*)d_in[0];
    const int*   term   = (const int*)d_in[1];
    const float* h0     = (const float*)d_in[2];
    const float* Wih    = (const float*)d_in[3];
    const float* Whh    = (const float*)d_in[4];
    const float* bih    = (const float*)d_in[5];
    const float* bhh    = (const float*)d_in[6];
    const float* fcw    = (const float*)d_in[7];
    const float* fcb    = (const float*)d_in[8];

    char* ws = (char*)d_ws;
    _Float16* xpw   = (_Float16*)(ws + XPW_OFF);
    _Float16* wih_h = (_Float16*)(ws + WIH_OFF);
    _Float16* whh_h = (_Float16*)(ws + WHH_OFF);
    _Float16* fcw_h = (_Float16*)(ws + FCW_OFF);
    float*    bias2 = (float*)(ws + BIAS_OFF);
    _Float16* wstr  = (_Float16*)(ws + WSTR_OFF);

    conv_w<<<1024, 256, 0, stream>>>(Wih, Whh, fcw, bih, bhh, wih_h, whh_h, fcw_h, bias2, wstr);
    gemm_xproj<<<2048, 256, 0, stream>>>(states, wih_h, bias2, xpw);
    rnn_scan3<<<32, 512, 0, stream>>>(xpw, whh_h, wstr, term, h0, (float*)d_out);
    gemm_logits<<<512, 512, 0, stream>>>((const _Float16*)d_out, fcw_h, fcb, (float*)d_out);
}